// Round 14
// baseline (48.971 us; speedup 1.0000x reference)
//
#include <hip/hip_runtime.h>
#include <hip/hip_bf16.h>

// Local (trunked) attention, MI355X gfx950.
// B=1, H=16, N=16384, d=64 fp32; 32-query trunks x 128-key window, pad_left=48.
// Block = 4 waves = 4 consecutive trunks of one head; 224-row window union.
// K and V have DISJOINT lifetimes (K read only in S^T, V only in PV), so they
// OVERLAY one 28.7 KB LDS buffer: stage K -> barrier -> S^T+softmax+P-pack ->
// barrier (WAR) -> stage V same buffer -> barrier -> PV. Halved LDS doubles
// resident blocks (4/CU, 16 waves/CU with VGPR<=128) so the V-stage stall
// overlaps other blocks' compute. K: row-major XOR-swizzled ds_read_b128.
// V: 4x16 subtiles via ds_read_b64_tr_b16. Swapped-QK^T 32x32 MFMA, per-lane
// softmax, P normalized in the in-register pack (cvt_pkrtz + permlane32_swap).

typedef _Float16 f16x8 __attribute__((ext_vector_type(8)));
typedef _Float16 f16x4 __attribute__((ext_vector_type(4)));
typedef float f32x16 __attribute__((ext_vector_type(16)));
typedef unsigned int u32;
typedef u32 u32x4 __attribute__((ext_vector_type(4)));

#define NSEQ   16384
#define DHEAD  64
#define LOG2E  1.44269504088896340736f
#define TRB    4                 // trunks per block
#define BQ     (TRB * 32)        // 128 queries per block
#define WROWS  (BQ + 96)         // 224 staged rows
#define RSTR   128               // K row stride (bytes, 64 f16)
#define KBYTES (WROWS * RSTR)    // 28672 shared by K then V (overlay)

__device__ __forceinline__ int swz(int r) {
  return ((r & 7) << 4) | ((r & 8) << 3);   // permute 16B-slots within a row
}

__device__ __forceinline__ u32 pk2(float a, float b) {
  auto h2 = __builtin_amdgcn_cvt_pkrtz(a, b);
  return __builtin_bit_cast(u32, h2);
}

__device__ __forceinline__ void plswap(u32& a, u32& b) {
#if __has_builtin(__builtin_amdgcn_permlane32_swap)
  typedef u32 u32x2 __attribute__((ext_vector_type(2)));
  u32x2 r = __builtin_amdgcn_permlane32_swap(a, b, false, false);
  a = r[0]; b = r[1];
#else
  const int hi = (threadIdx.x & 63) >> 5;
  u32 sa = (u32)__shfl_xor((int)a, 32);
  u32 sb = (u32)__shfl_xor((int)b, 32);
  u32 na = hi ? sb : a;
  u32 nb = hi ? b : sa;
  a = na; b = nb;
#endif
}

// 8 transpose-reads (one 32-key tile x full d), one wait.
// va = buffer + pair-of-key16-blocks base + lane*8.
__device__ __forceinline__ void tr8(u32 va, f16x4 (&t)[8]) {
  asm volatile("ds_read_b64_tr_b16 %0, %8 offset:0\n\t"
               "ds_read_b64_tr_b16 %1, %8 offset:1024\n\t"
               "ds_read_b64_tr_b16 %2, %8 offset:512\n\t"
               "ds_read_b64_tr_b16 %3, %8 offset:1536\n\t"
               "ds_read_b64_tr_b16 %4, %8 offset:2048\n\t"
               "ds_read_b64_tr_b16 %5, %8 offset:3072\n\t"
               "ds_read_b64_tr_b16 %6, %8 offset:2560\n\t"
               "ds_read_b64_tr_b16 %7, %8 offset:3584\n\t"
               "s_waitcnt lgkmcnt(0)"
               : "=&v"(t[0]), "=&v"(t[1]), "=&v"(t[2]), "=&v"(t[3]),
                 "=&v"(t[4]), "=&v"(t[5]), "=&v"(t[6]), "=&v"(t[7])
               : "v"(va));
  __builtin_amdgcn_sched_barrier(0);
}

// V subtile byte address (matches tr8's delivery order).
__device__ __forceinline__ int vaddr(int r, int c8) {
  const int dh = c8 >> 4;
  const int idx = ((r >> 2) & 1) * 8 + (dh >> 1) * 4 + ((r >> 3) & 1) * 2 + (dh & 1);
  return (r >> 4) * 2048 + idx * 128 + (r & 3) * 32 + (c8 & 15) * 2;
}

__global__ __launch_bounds__(256, 4) void local_attn_kernel(
    const float* __restrict__ q, const float* __restrict__ k,
    const float* __restrict__ v, float* __restrict__ out) {
  __shared__ __align__(128) char Bc[KBYTES];   // 28,672 B: K, then V (overlay)

  const int tid  = threadIdx.x;
  const int wave = tid >> 6;
  const int lane = tid & 63;
  const int l31  = lane & 31;
  const int hi   = lane >> 5;
  const int rsub = tid >> 3;          // 0..31 (stage row-sub)
  const int c8   = (tid & 7) * 8;     // stage f32 col

  int bid = blockIdx.x;
  bid = (bid & 7) * 256 + (bid >> 3);      // XCD swizzle (2048 % 8 == 0)
  const int h   = bid >> 7;                // head
  const int q0b = (bid & 127) << 7;        // block's first query row
  const int kg0 = q0b - 48;                // global row of LDS row 0
  const int q0  = q0b + wave * 32;         // this wave's trunk
  const int kb0 = q0 - 48;                 // wave's window start
  const int kvb = wave * 32;               // wave's local key base in LDS

  const float* __restrict__ qh = q + (size_t)h * NSEQ * DHEAD;
  const float* __restrict__ kh = k + (size_t)h * NSEQ * DHEAD;
  const float* __restrict__ vh = v + (size_t)h * NSEQ * DHEAD;

  // ---- Q loads + K stage -------------------------------------------------
  float4 qr[4][2];
  #pragma unroll
  for (int ks = 0; ks < 4; ++ks) {
    const float* p = qh + (size_t)(q0 + l31) * DHEAD + ks * 16 + hi * 8;
    qr[ks][0] = *reinterpret_cast<const float4*>(p);
    qr[ks][1] = *reinterpret_cast<const float4*>(p + 4);
  }
  #pragma unroll
  for (int it = 0; it < 7; ++it) {
    const int r = it * 32 + rsub;
    const int g = min(max(kg0 + r, 0), NSEQ - 1);   // clamp; masked in S
    const float* pk_ = kh + (size_t)g * DHEAD + c8;
    const float4 a = *reinterpret_cast<const float4*>(pk_);
    const float4 b = *reinterpret_cast<const float4*>(pk_ + 4);
    const u32x4 w = {pk2(a.x, a.y), pk2(a.z, a.w), pk2(b.x, b.y), pk2(b.z, b.w)};
    *reinterpret_cast<u32x4*>(Bc + ((r * RSTR + c8 * 2) ^ swz(r))) = w;
  }

  // ---- Q -> f16 fragments (log2e-scaled) --------------------------------
  f16x8 qf[4];
  #pragma unroll
  for (int ks = 0; ks < 4; ++ks) {
    qf[ks][0] = (_Float16)(qr[ks][0].x * LOG2E); qf[ks][1] = (_Float16)(qr[ks][0].y * LOG2E);
    qf[ks][2] = (_Float16)(qr[ks][0].z * LOG2E); qf[ks][3] = (_Float16)(qr[ks][0].w * LOG2E);
    qf[ks][4] = (_Float16)(qr[ks][1].x * LOG2E); qf[ks][5] = (_Float16)(qr[ks][1].y * LOG2E);
    qf[ks][6] = (_Float16)(qr[ks][1].z * LOG2E); qf[ks][7] = (_Float16)(qr[ks][1].w * LOG2E);
  }

  __syncthreads();                       // K staged

  // ---- S^T = K Q^T  (128 keys x 32 queries) -----------------------------
  // D[m=key][n=q]: col = lane&31 = q, row = (r&3)+8*(r>>2)+4*hi (+32*kt)
  f32x16 sacc[4] = {};
  #pragma unroll
  for (int ks = 0; ks < 4; ++ks) {
    #pragma unroll
    for (int kt = 0; kt < 4; ++kt) {
      const int row = kvb + kt * 32 + l31;
      const f16x8 kf = *reinterpret_cast<const f16x8*>(
          Bc + ((row * RSTR + (ks * 16 + hi * 8) * 2) ^ swz(row)));
      sacc[kt] = __builtin_amdgcn_mfma_f32_32x32x16_f16(kf, qf[ks], sacc[kt], 0, 0, 0);
    }
  }

  // ---- mask invalid keys (edge trunks only) -----------------------------
  if (q0 < 48 || q0 > NSEQ - 80) {
    #pragma unroll
    for (int kt = 0; kt < 4; ++kt)
      #pragma unroll
      for (int r = 0; r < 16; ++r) {
        const int key = kb0 + kt * 32 + (r & 3) + 8 * (r >> 2) + 4 * hi;
        if ((unsigned)key >= (unsigned)NSEQ) sacc[kt][r] = -1e30f;
      }
  }

  // ---- per-lane softmax over 128 keys (base-2 domain) -------------------
  float mx = -1e30f;
  #pragma unroll
  for (int kt = 0; kt < 4; ++kt)
    #pragma unroll
    for (int r = 0; r < 16; ++r) mx = fmaxf(mx, sacc[kt][r]);
  mx = fmaxf(mx, __shfl_xor(mx, 32));
  float sum = 0.f;
  #pragma unroll
  for (int kt = 0; kt < 4; ++kt)
    #pragma unroll
    for (int r = 0; r < 16; ++r) {
      const float p = exp2f(sacc[kt][r] - mx);
      sacc[kt][r] = p;
      sum += p;
    }
  sum += __shfl_xor(sum, 32);
  const float inv = 1.0f / sum;

  // ---- P -> A-fragments in-register, normalized HERE --------------------
  // (lane col = query only in the S^T phase; after PV lanes mean d-columns)
  f16x8 pa[4][2];
  #pragma unroll
  for (int kt = 0; kt < 4; ++kt) {
    u32 pk[8];
    #pragma unroll
    for (int c = 0; c < 8; ++c)
      pk[c] = pk2(sacc[kt][2 * c] * inv, sacc[kt][2 * c + 1] * inv);
    plswap(pk[0], pk[2]); plswap(pk[1], pk[3]);
    plswap(pk[4], pk[6]); plswap(pk[5], pk[7]);
    union { f16x8 f; u32 u[4]; } f0, f1;
    f0.u[0] = pk[0]; f0.u[1] = pk[1]; f0.u[2] = pk[2]; f0.u[3] = pk[3];
    f1.u[0] = pk[4]; f1.u[1] = pk[5]; f1.u[2] = pk[6]; f1.u[3] = pk[7];
    pa[kt][0] = f0.f;
    pa[kt][1] = f1.f;
  }

  __syncthreads();                       // all waves done READING K from Bc

  // ---- V stage into the SAME buffer (overlay) ---------------------------
  #pragma unroll
  for (int it = 0; it < 7; ++it) {
    const int r = it * 32 + rsub;
    const int g = min(max(kg0 + r, 0), NSEQ - 1);
    const float* pv_ = vh + (size_t)g * DHEAD + c8;
    const float4 a = *reinterpret_cast<const float4*>(pv_);
    const float4 b = *reinterpret_cast<const float4*>(pv_ + 4);
    const u32x4 w = {pk2(a.x, a.y), pk2(a.z, a.w), pk2(b.x, b.y), pk2(b.z, b.w)};
    *reinterpret_cast<u32x4*>(Bc + vaddr(r, c8)) = w;
  }

  __syncthreads();                       // V staged

  // ---- O = P V  (32 x 64), V via hardware transpose reads ---------------
  const u32 vb = (u32)(size_t)(&Bc[0]) + (u32)(lane * 8);
  f32x16 oacc[2] = {};
  #pragma unroll
  for (int kt = 0; kt < 4; ++kt) {
    f16x4 t[8];
    tr8(vb + (u32)(2 * (wave + kt) * 2048), t);
    union { f16x8 f; f16x4 h2[2]; } b00, b01, b10, b11;
    b00.h2[0] = t[0]; b00.h2[1] = t[1];   // keys 0..7 of tile, d 0..31
    b01.h2[0] = t[2]; b01.h2[1] = t[3];   // keys 0..7, d 32..63
    b10.h2[0] = t[4]; b10.h2[1] = t[5];   // keys 8..15, d 0..31
    b11.h2[0] = t[6]; b11.h2[1] = t[7];   // keys 8..15, d 32..63
    oacc[0] = __builtin_amdgcn_mfma_f32_32x32x16_f16(pa[kt][0], b00.f, oacc[0], 0, 0, 0);
    oacc[1] = __builtin_amdgcn_mfma_f32_32x32x16_f16(pa[kt][0], b01.f, oacc[1], 0, 0, 0);
    oacc[0] = __builtin_amdgcn_mfma_f32_32x32x16_f16(pa[kt][1], b10.f, oacc[0], 0, 0, 0);
    oacc[1] = __builtin_amdgcn_mfma_f32_32x32x16_f16(pa[kt][1], b11.f, oacc[1], 0, 0, 0);
  }

  // ---- store O (row = query = crow(r,hi); col = lane = d) ---------------
  float* __restrict__ oh = out + (size_t)h * NSEQ * DHEAD;
  #pragma unroll
  for (int r = 0; r < 16; ++r) {
    const int row = q0 + (r & 3) + 8 * (r >> 2) + 4 * hi;
    float* po = oh + (size_t)row * DHEAD + l31;
    po[0]  = oacc[0][r];
    po[32] = oacc[1][r];
  }
}

extern "C" void kernel_launch(void* const* d_in, const int* in_sizes, int n_in,
                              void* d_out, int out_size, void* d_ws, size_t ws_size,
                              hipStream_t stream) {
  const float* q = (const float*)d_in[0];
  const float* k = (const float*)d_in[1];
  const float* v = (const float*)d_in[2];
  float* out = (float*)d_out;
  dim3 grid(2048), block(256);   // block = 4 consecutive trunks of one head
  hipLaunchKernelGGL(local_attn_kernel, grid, block, 0, stream, q, k, v, out);
}

// Round 15
// 44.393 us; speedup vs baseline: 1.1031x; 1.1031x over previous
//
#include <hip/hip_runtime.h>
#include <hip/hip_bf16.h>

// Local (trunked) attention, MI355X gfx950.  [measured best: 44.4 us, round 8]
// B=1, H=16, N=16384, d=64 fp32; 32-query trunks x 128-key window, pad_left=48.
// Block = 4 waves = 4 consecutive trunks of one head; 224-row K/V window union
// staged to LDS as f16 in one up-front burst (deep memory-level parallelism).
// K: row-major XOR-swizzled, ds_read_b128 slices. V: 4x16-subtiled layout
// consumed via ds_read_b64_tr_b16 hardware transpose (per-lane base + lane*8;
// immediate offsets walk subtiles). Swapped-QK^T 32x32 MFMA structure,
// per-lane softmax (base-2 domain), P normalized in the in-register pack
// (cvt_pkrtz + permlane32_swap). At 44.4 us the kernel moves its 256 MB
// unique footprint at 5.8 TB/s = 91% of the measured 6.3 TB/s copy ceiling;
// occupancy/pipelining/async-split variants (rounds 9-14) all regressed.

typedef _Float16 f16x8 __attribute__((ext_vector_type(8)));
typedef _Float16 f16x4 __attribute__((ext_vector_type(4)));
typedef float f32x16 __attribute__((ext_vector_type(16)));
typedef unsigned int u32;
typedef u32 u32x4 __attribute__((ext_vector_type(4)));

#define NSEQ   16384
#define DHEAD  64
#define LOG2E  1.44269504088896340736f
#define TRB    4                 // trunks per block
#define BQ     (TRB * 32)        // 128 queries per block
#define WROWS  (BQ + 96)         // 224 staged rows
#define RSTR   128               // K row stride (bytes, 64 f16)
#define KBYTES (WROWS * RSTR)    // 28672 each for K and V

__device__ __forceinline__ int swz(int r) {
  return ((r & 7) << 4) | ((r & 8) << 3);   // permute 16B-slots within a row
}

__device__ __forceinline__ u32 pk2(float a, float b) {
  auto h2 = __builtin_amdgcn_cvt_pkrtz(a, b);
  return __builtin_bit_cast(u32, h2);
}

__device__ __forceinline__ void plswap(u32& a, u32& b) {
#if __has_builtin(__builtin_amdgcn_permlane32_swap)
  typedef u32 u32x2 __attribute__((ext_vector_type(2)));
  u32x2 r = __builtin_amdgcn_permlane32_swap(a, b, false, false);
  a = r[0]; b = r[1];
#else
  const int hi = (threadIdx.x & 63) >> 5;
  u32 sa = (u32)__shfl_xor((int)a, 32);
  u32 sb = (u32)__shfl_xor((int)b, 32);
  u32 na = hi ? sb : a;
  u32 nb = hi ? b : sa;
  a = na; b = nb;
#endif
}

// 8 transpose-reads (one 32-key tile x full d), one wait.
// va = Vc + pair-of-key16-blocks base + lane*8 (per-lane!).
__device__ __forceinline__ void tr8(u32 va, f16x4 (&t)[8]) {
  asm volatile("ds_read_b64_tr_b16 %0, %8 offset:0\n\t"
               "ds_read_b64_tr_b16 %1, %8 offset:1024\n\t"
               "ds_read_b64_tr_b16 %2, %8 offset:512\n\t"
               "ds_read_b64_tr_b16 %3, %8 offset:1536\n\t"
               "ds_read_b64_tr_b16 %4, %8 offset:2048\n\t"
               "ds_read_b64_tr_b16 %5, %8 offset:3072\n\t"
               "ds_read_b64_tr_b16 %6, %8 offset:2560\n\t"
               "ds_read_b64_tr_b16 %7, %8 offset:3584\n\t"
               "s_waitcnt lgkmcnt(0)"
               : "=&v"(t[0]), "=&v"(t[1]), "=&v"(t[2]), "=&v"(t[3]),
                 "=&v"(t[4]), "=&v"(t[5]), "=&v"(t[6]), "=&v"(t[7])
               : "v"(va));
  __builtin_amdgcn_sched_barrier(0);
}

// Stage 224 rows x 64 cols f32 -> LDS f16, K layout (row-major + XOR swizzle).
__device__ __forceinline__ void stageK(const float* __restrict__ src, int grow0,
                                       char* __restrict__ dst, int tid) {
  const int rsub = tid >> 3;          // 0..31
  const int c8   = (tid & 7) * 8;     // f32 col
  #pragma unroll
  for (int it = 0; it < 7; ++it) {
    const int r = it * 32 + rsub;
    const int g = min(max(grow0 + r, 0), NSEQ - 1);   // clamp; masked in S
    const float* p = src + (size_t)g * DHEAD + c8;
    const float4 a = *reinterpret_cast<const float4*>(p);
    const float4 b = *reinterpret_cast<const float4*>(p + 4);
    const u32x4 w = {pk2(a.x, a.y), pk2(a.z, a.w), pk2(b.x, b.y), pk2(b.z, b.w)};
    *reinterpret_cast<u32x4*>(dst + ((r * RSTR + c8 * 2) ^ swz(r))) = w;
  }
}

// Stage V into 4x16 subtiles matching tr8's delivery:
// within each 2KB key-16 block, subtile idx =
//   ((kk>>2)&1)*8 + (dh>>1)*4 + ((kk>>3)&1)*2 + (dh&1),  kk=r&15, dh=d>>4.
__device__ __forceinline__ void stageV(const float* __restrict__ src, int grow0,
                                       char* __restrict__ dst, int tid) {
  const int rsub = tid >> 3;
  const int c8   = (tid & 7) * 8;
  const int dh   = c8 >> 4;
  #pragma unroll
  for (int it = 0; it < 7; ++it) {
    const int r = it * 32 + rsub;
    const int g = min(max(grow0 + r, 0), NSEQ - 1);
    const float* p = src + (size_t)g * DHEAD + c8;
    const float4 a = *reinterpret_cast<const float4*>(p);
    const float4 b = *reinterpret_cast<const float4*>(p + 4);
    const u32x4 w = {pk2(a.x, a.y), pk2(a.z, a.w), pk2(b.x, b.y), pk2(b.z, b.w)};
    const int idx = ((r >> 2) & 1) * 8 + (dh >> 1) * 4 + ((r >> 3) & 1) * 2 + (dh & 1);
    const int addr = (r >> 4) * 2048 + idx * 128 + (r & 3) * 32 + (c8 & 15) * 2;
    *reinterpret_cast<u32x4*>(dst + addr) = w;
  }
}

__global__ __launch_bounds__(256, 2) void local_attn_kernel(
    const float* __restrict__ q, const float* __restrict__ k,
    const float* __restrict__ v, float* __restrict__ out) {
  __shared__ __align__(128) char smem[2 * KBYTES];   // 57,344 B: K then V
  char* const Kc = smem;
  char* const Vc = smem + KBYTES;

  const int tid  = threadIdx.x;
  const int wave = tid >> 6;
  const int lane = tid & 63;
  const int l31  = lane & 31;
  const int hi   = lane >> 5;

  int bid = blockIdx.x;
  bid = (bid & 7) * 256 + (bid >> 3);      // XCD swizzle (2048 % 8 == 0)
  const int h   = bid >> 7;                // head
  const int q0b = (bid & 127) << 7;        // block's first query row
  const int kg0 = q0b - 48;                // global row of LDS row 0
  const int q0  = q0b + wave * 32;         // this wave's trunk
  const int kb0 = q0 - 48;                 // wave's window start
  const int kvb = wave * 32;               // wave's local key base in LDS

  const float* __restrict__ qh = q + (size_t)h * NSEQ * DHEAD;
  const float* __restrict__ kh = k + (size_t)h * NSEQ * DHEAD;
  const float* __restrict__ vh = v + (size_t)h * NSEQ * DHEAD;

  // ---- Q raw loads issued before staging (latency hides under stage) ----
  float4 qr[4][2];
  #pragma unroll
  for (int ks = 0; ks < 4; ++ks) {
    const float* p = qh + (size_t)(q0 + l31) * DHEAD + ks * 16 + hi * 8;
    qr[ks][0] = *reinterpret_cast<const float4*>(p);
    qr[ks][1] = *reinterpret_cast<const float4*>(p + 4);
  }

  // ---- cooperative K/V staging (single deep burst) ----------------------
  stageK(kh, kg0, Kc, tid);
  stageV(vh, kg0, Vc, tid);
  __syncthreads();

  // ---- S^T = K Q^T  (128 keys x 32 queries) -----------------------------
  // D[m=key][n=q]: col = lane&31 = q, row = (r&3)+8*(r>>2)+4*hi (+32*kt)
  f32x16 sacc[4] = {};
  #pragma unroll
  for (int ks = 0; ks < 4; ++ks) {
    f16x8 qf;
    qf[0] = (_Float16)(qr[ks][0].x * LOG2E); qf[1] = (_Float16)(qr[ks][0].y * LOG2E);
    qf[2] = (_Float16)(qr[ks][0].z * LOG2E); qf[3] = (_Float16)(qr[ks][0].w * LOG2E);
    qf[4] = (_Float16)(qr[ks][1].x * LOG2E); qf[5] = (_Float16)(qr[ks][1].y * LOG2E);
    qf[6] = (_Float16)(qr[ks][1].z * LOG2E); qf[7] = (_Float16)(qr[ks][1].w * LOG2E);
    #pragma unroll
    for (int kt = 0; kt < 4; ++kt) {
      const int row = kvb + kt * 32 + l31;
      const f16x8 kf = *reinterpret_cast<const f16x8*>(
          Kc + ((row * RSTR + (ks * 16 + hi * 8) * 2) ^ swz(row)));
      sacc[kt] = __builtin_amdgcn_mfma_f32_32x32x16_f16(kf, qf, sacc[kt], 0, 0, 0);
    }
  }

  // ---- mask invalid keys (edge trunks only) -----------------------------
  if (q0 < 48 || q0 > NSEQ - 80) {
    #pragma unroll
    for (int kt = 0; kt < 4; ++kt)
      #pragma unroll
      for (int r = 0; r < 16; ++r) {
        const int key = kb0 + kt * 32 + (r & 3) + 8 * (r >> 2) + 4 * hi;
        if ((unsigned)key >= (unsigned)NSEQ) sacc[kt][r] = -1e30f;
      }
  }

  // ---- per-lane softmax over 128 keys (base-2 domain) -------------------
  float mx = -1e30f;
  #pragma unroll
  for (int kt = 0; kt < 4; ++kt)
    #pragma unroll
    for (int r = 0; r < 16; ++r) mx = fmaxf(mx, sacc[kt][r]);
  mx = fmaxf(mx, __shfl_xor(mx, 32));
  float sum = 0.f;
  #pragma unroll
  for (int kt = 0; kt < 4; ++kt)
    #pragma unroll
    for (int r = 0; r < 16; ++r) {
      const float p = exp2f(sacc[kt][r] - mx);
      sacc[kt][r] = p;
      sum += p;
    }
  sum += __shfl_xor(sum, 32);
  const float inv = 1.0f / sum;

  // ---- P -> A-fragments in-register, normalized HERE --------------------
  // (lane col = query only in the S^T phase; after PV lanes mean d-columns)
  f16x8 pa[4][2];
  #pragma unroll
  for (int kt = 0; kt < 4; ++kt) {
    u32 pk[8];
    #pragma unroll
    for (int c = 0; c < 8; ++c)
      pk[c] = pk2(sacc[kt][2 * c] * inv, sacc[kt][2 * c + 1] * inv);
    plswap(pk[0], pk[2]); plswap(pk[1], pk[3]);
    plswap(pk[4], pk[6]); plswap(pk[5], pk[7]);
    union { f16x8 f; u32 u[4]; } f0, f1;
    f0.u[0] = pk[0]; f0.u[1] = pk[1]; f0.u[2] = pk[2]; f0.u[3] = pk[3];
    f1.u[0] = pk[4]; f1.u[1] = pk[5]; f1.u[2] = pk[6]; f1.u[3] = pk[7];
    pa[kt][0] = f0.f;
    pa[kt][1] = f1.f;
  }

  // ---- O = P V  (32 x 64), V via hardware transpose reads ---------------
  const u32 vb = (u32)(size_t)Vc + (u32)(lane * 8);
  f32x16 oacc[2] = {};
  #pragma unroll
  for (int kt = 0; kt < 4; ++kt) {
    f16x4 t[8];
    tr8(vb + (u32)(2 * (wave + kt) * 2048), t);
    union { f16x8 f; f16x4 h2[2]; } b00, b01, b10, b11;
    b00.h2[0] = t[0]; b00.h2[1] = t[1];   // keys 0..7 of tile, d 0..31
    b01.h2[0] = t[2]; b01.h2[1] = t[3];   // keys 0..7, d 32..63
    b10.h2[0] = t[4]; b10.h2[1] = t[5];   // keys 8..15, d 0..31
    b11.h2[0] = t[6]; b11.h2[1] = t[7];   // keys 8..15, d 32..63
    oacc[0] = __builtin_amdgcn_mfma_f32_32x32x16_f16(pa[kt][0], b00.f, oacc[0], 0, 0, 0);
    oacc[1] = __builtin_amdgcn_mfma_f32_32x32x16_f16(pa[kt][0], b01.f, oacc[1], 0, 0, 0);
    oacc[0] = __builtin_amdgcn_mfma_f32_32x32x16_f16(pa[kt][1], b10.f, oacc[0], 0, 0, 0);
    oacc[1] = __builtin_amdgcn_mfma_f32_32x32x16_f16(pa[kt][1], b11.f, oacc[1], 0, 0, 0);
  }

  // ---- store O (row = query = crow(r,hi); col = lane = d) ---------------
  float* __restrict__ oh = out + (size_t)h * NSEQ * DHEAD;
  #pragma unroll
  for (int r = 0; r < 16; ++r) {
    const int row = q0 + (r & 3) + 8 * (r >> 2) + 4 * hi;
    float* po = oh + (size_t)row * DHEAD + l31;
    po[0]  = oacc[0][r];
    po[32] = oacc[1][r];
  }
}

extern "C" void kernel_launch(void* const* d_in, const int* in_sizes, int n_in,
                              void* d_out, int out_size, void* d_ws, size_t ws_size,
                              hipStream_t stream) {
  const float* q = (const float*)d_in[0];
  const float* k = (const float*)d_in[1];
  const float* v = (const float*)d_in[2];
  float* out = (float*)d_out;
  dim3 grid(2048), block(256);   // block = 4 consecutive trunks of one head
  hipLaunchKernelGGL(local_attn_kernel, grid, block, 0, stream, q, k, v, out);
}